// Round 14
// baseline (255.828 us; speedup 1.0000x reference)
//
#include <hip/hip_runtime.h>
#include <hip/hip_bf16.h>
#include <math.h>

#define T_LEN 1024
#define D_MODEL 1024
#define NKV 4
#define REP 4
#define DH 64
#define NB 63
#define TOPN 8
#define KVD 256        // NKV*DH
#define LDIM2 1328     // virtual concatenated width without k_cmp
#define TQ 16          // query tile for fused kernel
#define SGN 4          // n-group for summarize

typedef __attribute__((ext_vector_type(8))) short bf16x8;
typedef __attribute__((ext_vector_type(4))) float f32x4;

__device__ __forceinline__ float gelu_exact(float x) {
    return 0.5f * x * (1.0f + erff(x * 0.70710678118654752f));
}
__device__ __forceinline__ float sigmoidf(float x) {
    return 1.0f / (1.0f + expf(-x));
}
// pack 8 f32 -> 8 bf16 via HW v_cvt_pk_bf16_f32 (RNE)
__device__ __forceinline__ bf16x8 cvt8(float4 a0, float4 a1) {
    union { __hip_bfloat162 v; short2 s; } u0, u1, u2, u3;
    u0.v = __float22bfloat162_rn(make_float2(a0.x, a0.y));
    u1.v = __float22bfloat162_rn(make_float2(a0.z, a0.w));
    u2.v = __float22bfloat162_rn(make_float2(a1.x, a1.y));
    u3.v = __float22bfloat162_rn(make_float2(a1.z, a1.w));
    bf16x8 r;
    r[0] = u0.s.x; r[1] = u0.s.y; r[2] = u1.s.x; r[3] = u1.s.y;
    r[4] = u2.s.x; r[5] = u2.s.y; r[6] = u3.s.x; r[7] = u3.s.y;
    return r;
}

// ---------------------------------------------------------------------------
// Merged projection dispatch, grid (25,16), dynamic LDS 17408 B (r13 proven:
// register-prefetch pipelining on the k-loop).
// ---------------------------------------------------------------------------
__global__ __launch_bounds__(256) void proj_all(
    const float* __restrict__ x,
    const float* __restrict__ gate_w, const float* __restrict__ gate_b,
    const float* __restrict__ wk_cmp, const float* __restrict__ wv_cmp,
    const float* __restrict__ wk_slc, const float* __restrict__ wv_slc,
    const float* __restrict__ wk_win, const float* __restrict__ wv_win,
    float* __restrict__ gates_lin, float* __restrict__ k_cmp,
    float* __restrict__ v_cmp,
    float* __restrict__ k_slc, float* __restrict__ v_slc,
    float* __restrict__ k_win, float* __restrict__ v_win)
{
    extern __shared__ char smem[];
    const int tid = threadIdx.x;
    const int m0 = blockIdx.y * 64;

    if (blockIdx.x < 21) {
        typedef unsigned short row40[40];
        row40* As = (row40*)smem;
        row40* Bs = (row40*)(smem + 64 * 40 * sizeof(unsigned short));
        const int lane = tid & 63;
        const int w = tid >> 6;
        const int n0 = blockIdx.x * 64;

        const int srow = tid >> 2;
        const int sseg = tid & 3;
        const float* ga = x + (m0 + srow) * D_MODEL + sseg * 8;
        const float* gb;
        {
            int nn = n0 + srow;
            if (nn < 48)        gb = gate_w + nn * D_MODEL;
            else if (nn < 304)  gb = wv_cmp + (nn - 48) * D_MODEL;
            else if (nn < 560)  gb = wk_slc + (nn - 304) * D_MODEL;
            else if (nn < 816)  gb = wv_slc + (nn - 560) * D_MODEL;
            else if (nn < 1072) gb = wk_win + (nn - 816) * D_MODEL;
            else if (nn < 1328) gb = wv_win + (nn - 1072) * D_MODEL;
            else                gb = gate_w;
            gb += sseg * 8;
        }

        f32x4 acc[4] = {};
        const int arow = (w << 4) + (lane & 15);
        const int kk8  = (lane >> 4) * 8;

        float4 a0 = *(const float4*)(ga);
        float4 a1 = *(const float4*)(ga + 4);
        float4 b0 = *(const float4*)(gb);
        float4 b1 = *(const float4*)(gb + 4);

        for (int k0 = 0; k0 < D_MODEL; k0 += 32) {
            bf16x8 ap = cvt8(a0, a1);
            bf16x8 bp = cvt8(b0, b1);
            __syncthreads();
            *(bf16x8*)&As[srow][sseg * 8] = ap;
            *(bf16x8*)&Bs[srow][sseg * 8] = bp;
            __syncthreads();
            if (k0 + 32 < D_MODEL) {
                a0 = *(const float4*)(ga + k0 + 32);
                a1 = *(const float4*)(ga + k0 + 36);
                b0 = *(const float4*)(gb + k0 + 32);
                b1 = *(const float4*)(gb + k0 + 36);
            }
            bf16x8 af = *(bf16x8*)&As[arow][kk8];
            #pragma unroll
            for (int j = 0; j < 4; ++j) {
                bf16x8 bfr = *(bf16x8*)&Bs[j * 16 + (lane & 15)][kk8];
                acc[j] = __builtin_amdgcn_mfma_f32_16x16x32_bf16(af, bfr, acc[j], 0, 0, 0);
            }
        }

        #pragma unroll
        for (int j = 0; j < 4; ++j) {
            int col = n0 + j * 16 + (lane & 15);
            if (col >= LDIM2) continue;
            int rbase = m0 + (w << 4) + (lane >> 4) * 4;
            float* dst; int cc; int stride = 256; float badd = 0.0f;
            if (col < 48)        { dst = gates_lin; cc = col;        stride = 48; badd = gate_b[col]; }
            else if (col < 304)  { dst = v_cmp;     cc = col - 48;   }
            else if (col < 560)  { dst = k_slc;     cc = col - 304;  }
            else if (col < 816)  { dst = v_slc;     cc = col - 560;  }
            else if (col < 1072) { dst = k_win;     cc = col - 816;  }
            else                 { dst = v_win;     cc = col - 1072; }
            #pragma unroll
            for (int rg = 0; rg < 4; ++rg)
                dst[(rbase + rg) * stride + cc] = acc[j][rg] + badd;
        }
    } else {
        typedef float row68[68];
        row68* As = (row68*)smem;
        row68* Bs = (row68*)(smem + 32 * 68 * sizeof(float));
        const int tx = tid & 15, ty = tid >> 4;
        const int n0 = (blockIdx.x - 21) * 64;
        const int srow = tid >> 2, sseg = tid & 3;
        const float* ga = x + (m0 + srow) * D_MODEL + sseg * 8;
        const float* gb = wk_cmp + (n0 + srow) * D_MODEL + sseg * 8;

        float acc[4][4] = {};
        float4 a0 = *(const float4*)(ga);
        float4 a1 = *(const float4*)(ga + 4);
        float4 b0 = *(const float4*)(gb);
        float4 b1 = *(const float4*)(gb + 4);

        for (int k0 = 0; k0 < D_MODEL; k0 += 32) {
            __syncthreads();
            As[sseg*8+0][srow]=a0.x; As[sseg*8+1][srow]=a0.y; As[sseg*8+2][srow]=a0.z; As[sseg*8+3][srow]=a0.w;
            As[sseg*8+4][srow]=a1.x; As[sseg*8+5][srow]=a1.y; As[sseg*8+6][srow]=a1.z; As[sseg*8+7][srow]=a1.w;
            Bs[sseg*8+0][srow]=b0.x; Bs[sseg*8+1][srow]=b0.y; Bs[sseg*8+2][srow]=b0.z; Bs[sseg*8+3][srow]=b0.w;
            Bs[sseg*8+4][srow]=b1.x; Bs[sseg*8+5][srow]=b1.y; Bs[sseg*8+6][srow]=b1.z; Bs[sseg*8+7][srow]=b1.w;
            __syncthreads();
            if (k0 + 32 < D_MODEL) {
                a0 = *(const float4*)(ga + k0 + 32);
                a1 = *(const float4*)(ga + k0 + 36);
                b0 = *(const float4*)(gb + k0 + 32);
                b1 = *(const float4*)(gb + k0 + 36);
            }
            #pragma unroll
            for (int kk = 0; kk < 32; ++kk) {
                float4 a4 = *(const float4*)&As[kk][ty * 4];
                float4 b4 = *(const float4*)&Bs[kk][tx * 4];
                acc[0][0] += a4.x*b4.x; acc[0][1] += a4.x*b4.y; acc[0][2] += a4.x*b4.z; acc[0][3] += a4.x*b4.w;
                acc[1][0] += a4.y*b4.x; acc[1][1] += a4.y*b4.y; acc[1][2] += a4.y*b4.z; acc[1][3] += a4.y*b4.w;
                acc[2][0] += a4.z*b4.x; acc[2][1] += a4.z*b4.y; acc[2][2] += a4.z*b4.z; acc[2][3] += a4.z*b4.w;
                acc[3][0] += a4.w*b4.x; acc[3][1] += a4.w*b4.y; acc[3][2] += a4.w*b4.z; acc[3][3] += a4.w*b4.w;
            }
        }
        #pragma unroll
        for (int i = 0; i < 4; ++i) {
            int mm = m0 + ty * 4 + i;
            #pragma unroll
            for (int j = 0; j < 4; ++j)
                k_cmp[mm * KVD + n0 + tx * 4 + j] = acc[i][j];
        }
    }
}

// ---------------------------------------------------------------------------
// Block summaries, 4-wide n-tiling (r13 proven). grid (16, 4, 2).
// ---------------------------------------------------------------------------
__global__ __launch_bounds__(256) void nsa_summarize(
    const float* __restrict__ k_cmp, const float* __restrict__ v_cmp,
    const float* __restrict__ block_pos,
    const float* __restrict__ ck1_w, const float* __restrict__ ck1_b,
    const float* __restrict__ ck2_w, const float* __restrict__ ck2_b,
    const float* __restrict__ cv1_w, const float* __restrict__ cv1_b,
    const float* __restrict__ cv2_w, const float* __restrict__ cv2_b,
    float* __restrict__ ksum, float* __restrict__ vsum)
{
    const int ng = blockIdx.x, k = blockIdx.y, which = blockIdx.z;
    const int n0 = ng * SGN;
    const float* src = which ? v_cmp : k_cmp;
    const float* w1  = which ? cv1_w : ck1_w;
    const float* b1  = which ? cv1_b : ck1_b;
    const float* w2  = which ? cv2_w : ck2_w;
    const float* b2  = which ? cv2_b : ck2_b;
    float* dst       = which ? vsum  : ksum;

    __shared__ float flat[SGN][4 * 516];
    __shared__ float hidden[SGN][DH];
    const int tid = threadIdx.x;

    #pragma unroll
    for (int j = 0; j < SGN; ++j) {
        int n = n0 + j; if (n >= NB) n = NB - 1;
        int start = n * 16;
        for (int e = tid; e < 512; e += 256) {
            int p = e >> 4, d4 = e & 15;
            float4 s = *(const float4*)(src + ((start + p) * NKV + k) * DH + d4 * 4);
            float4 bp = *(const float4*)(block_pos + p * DH + d4 * 4);
            float4 r; r.x = s.x + bp.x; r.y = s.y + bp.y; r.z = s.z + bp.z; r.w = s.w + bp.w;
            *(float4*)&flat[j][(p >> 3) * 516 + (p & 7) * 64 + d4 * 4] = r;
        }
    }
    __syncthreads();
    {
        int h = tid >> 2, part = tid & 3;
        const float* wr = w1 + h * 2048 + part * 512;
        float s[SGN] = {0.f, 0.f, 0.f, 0.f};
        for (int jj = 0; jj < 512; jj += 4) {
            float4 b = *(const float4*)(wr + jj);
            #pragma unroll
            for (int j = 0; j < SGN; ++j) {
                float4 a = *(const float4*)&flat[j][part * 516 + jj];
                s[j] += a.x * b.x + a.y * b.y + a.z * b.z + a.w * b.w;
            }
        }
        #pragma unroll
        for (int j = 0; j < SGN; ++j) {
            float v = s[j];
            v += __shfl_xor(v, 1);
            v += __shfl_xor(v, 2);
            if (part == 0) hidden[j][h] = gelu_exact(v + b1[h]);
        }
    }
    __syncthreads();
    {
        int dh = tid >> 2, part = tid & 3;
        const float* wr = w2 + dh * 64 + part * 16;
        float s[SGN] = {0.f, 0.f, 0.f, 0.f};
        #pragma unroll
        for (int hh = 0; hh < 16; ++hh) {
            float b = wr[hh];
            #pragma unroll
            for (int j = 0; j < SGN; ++j)
                s[j] += hidden[j][part * 16 + hh] * b;
        }
        #pragma unroll
        for (int j = 0; j < SGN; ++j) {
            float v = s[j];
            v += __shfl_xor(v, 1);
            v += __shfl_xor(v, 2);
            if (part == 0 && (n0 + j) < NB)
                dst[((n0 + j) * NKV + k) * DH + dh] = v + b2[dh];
        }
    }
}

// ---------------------------------------------------------------------------
// Flash machinery (r13 proven: online softmax, count weights, ctz chunk walk,
// register-prefetch pipelining).
// ---------------------------------------------------------------------------
template<bool SEL>
__device__ __forceinline__ float weightf(int p, int tq, unsigned mk0, unsigned mk1) {
    if (SEL) {
        int b = p >> 4;
        unsigned c = (b < 32) ? ((mk0 >> b) & 1u) : ((mk1 >> (b - 32)) & 1u);
        int b2 = b - 1;
        if (b2 >= 0)
            c += (b2 < 32) ? ((mk0 >> b2) & 1u) : ((mk1 >> (b2 - 32)) & 1u);
        return (p <= tq) ? (float)c : 0.0f;
    } else {
        return (p <= tq && p > tq - 256) ? 1.0f : 0.0f;
    }
}

struct KRegs { float4 a0, a1, a2, a3; };
struct VRegs { float4 x0, x1, y0, y1; };

__device__ __forceinline__ KRegs load_k_regs(const float* kptr, int k, int cb, int tid) {
    int row = tid >> 2, dseg = tid & 3;
    const float* src = kptr + (((cb << 6) + row) * NKV + k) * DH + dseg * 16;
    KRegs r;
    r.a0 = *(const float4*)(src);
    r.a1 = *(const float4*)(src + 4);
    r.a2 = *(const float4*)(src + 8);
    r.a3 = *(const float4*)(src + 12);
    return r;
}
__device__ __forceinline__ void write_k(const KRegs& r, int tid, unsigned short (*ks)[72]) {
    int row = tid >> 2, dseg = tid & 3;
    *(bf16x8*)&ks[row][dseg * 16]     = cvt8(r.a0, r.a1);
    *(bf16x8*)&ks[row][dseg * 16 + 8] = cvt8(r.a2, r.a3);
}
__device__ __forceinline__ VRegs load_v_regs(const float* vptr, int k, int cb, int tid) {
    int l = tid & 63, wv = tid >> 6;
    int dbase = wv * 16 + ((l >> 5) << 3);
    int pp = (l & 31) * 2;
    const float* v0 = vptr + (((cb << 6) + pp) * NKV + k) * DH + dbase;
    const float* v1 = v0 + NKV * DH;
    VRegs r;
    r.x0 = *(const float4*)v0; r.x1 = *(const float4*)(v0 + 4);
    r.y0 = *(const float4*)v1; r.y1 = *(const float4*)(v1 + 4);
    return r;
}
__device__ __forceinline__ void write_v(const VRegs& r, int tid, unsigned short (*vt)[88]) {
    int l = tid & 63, wv = tid >> 6;
    int dbase = wv * 16 + ((l >> 5) << 3);
    int pp = (l & 31) * 2;
    union { __hip_bfloat162 v; unsigned u; } t_;
    t_.v = __float22bfloat162_rn(make_float2(r.x0.x, r.y0.x)); *(unsigned*)&vt[dbase + 0][pp] = t_.u;
    t_.v = __float22bfloat162_rn(make_float2(r.x0.y, r.y0.y)); *(unsigned*)&vt[dbase + 1][pp] = t_.u;
    t_.v = __float22bfloat162_rn(make_float2(r.x0.z, r.y0.z)); *(unsigned*)&vt[dbase + 2][pp] = t_.u;
    t_.v = __float22bfloat162_rn(make_float2(r.x0.w, r.y0.w)); *(unsigned*)&vt[dbase + 3][pp] = t_.u;
    t_.v = __float22bfloat162_rn(make_float2(r.x1.x, r.y1.x)); *(unsigned*)&vt[dbase + 4][pp] = t_.u;
    t_.v = __float22bfloat162_rn(make_float2(r.x1.y, r.y1.y)); *(unsigned*)&vt[dbase + 5][pp] = t_.u;
    t_.v = __float22bfloat162_rn(make_float2(r.x1.z, r.y1.z)); *(unsigned*)&vt[dbase + 6][pp] = t_.u;
    t_.v = __float22bfloat162_rn(make_float2(r.x1.w, r.y1.w)); *(unsigned*)&vt[dbase + 7][pp] = t_.u;
}

template<bool SEL>
__device__ __forceinline__ void flash_branch(
    const float* kptr, const float* vptr, int k, int t0, int c0, int c1,
    unsigned cmask,
    int tid, int quad, int col,
    bf16x8 qf0, bf16x8 qf1,
    unsigned short (*ks)[72], unsigned short (*vt)[88], float (*ps)[76],
    const unsigned int (*selm)[2],
    f32x4 (&O)[4])
{
    unsigned mk0[4] = {0,0,0,0}, mk1[4] = {0,0,0,0};
    int tq[4];
    #pragma unroll
    for (int g = 0; g < 4; ++g) {
        int row = quad * 4 + g;
        tq[g] = t0 + row;
        if (SEL) { mk0[g] = selm[row][0]; mk1[g] = selm[row][1]; }
    }

    float M[4] = {-1e30f, -1e30f, -1e30f, -1e30f};
    float l[4] = {0.f, 0.f, 0.f, 0.f};
    f32x4 z = {0.f, 0.f, 0.f, 0.f};
    O[0] = z; O[1] = z; O[2] = z; O[3] = z;

    unsigned rem = cmask & ((2u << c1) - 1u);
    rem = (rem >> c0) << c0;

    if (rem) {
        int cb = __builtin_ctz(rem);
        KRegs kr = load_k_regs(kptr, k, cb, tid);
        VRegs vr = load_v_regs(vptr, k, cb, tid);
        while (true) {
            unsigned rem2 = rem & (rem - 1);
            int nxt = rem2 ? __builtin_ctz(rem2) : -1;
            __syncthreads();
            write_k(kr, tid, ks);
            write_v(vr, tid, vt);
            __syncthreads();
            if (nxt >= 0) {
                kr = load_k_regs(kptr, k, nxt, tid);
                vr = load_v_regs(vptr, k, nxt, tid);
            }

            float sv[4][4];
            #pragma unroll
            for (int nt = 0; nt < 4; ++nt) {
                bf16x8 b0 = *(const bf16x8*)&ks[nt * 16 + col][quad * 8];
                bf16x8 b1 = *(const bf16x8*)&ks[nt * 16 + col][32 + quad * 8];
                f32x4 sc = {0.f, 0.f, 0.f, 0.f};
                sc = __builtin_amdgcn_mfma_f32_16x16x32_bf16(qf0, b0, sc, 0, 0, 0);
                sc = __builtin_amdgcn_mfma_f32_16x16x32_bf16(qf1, b1, sc, 0, 0, 0);
                #pragma unroll
                for (int g = 0; g < 4; ++g) sv[nt][g] = sc[g] * 0.125f;
            }
            #pragma unroll
            for (int g = 0; g < 4; ++g) {
                float cm = -1e30f;
                #pragma unroll
                for (int nt = 0; nt < 4; ++nt) {
                    int p = (cb << 6) + nt * 16 + col;
                    float w = weightf<SEL>(p, tq[g], mk0[g], mk1[g]);
                    if (w > 0.0f) cm = fmaxf(cm, sv[nt][g]);
                }
                cm = fmaxf(cm, __shfl_xor(cm, 1));
                cm = fmaxf(cm, __shfl_xor(cm, 2));
                cm = fmaxf(cm, __shfl_xor(cm, 4));
                cm = fmaxf(cm, __shfl_xor(cm, 8));
                float nM = fmaxf(M[g], cm);
                float sc_ = expf(M[g] - nM);
                l[g] *= sc_;
                M[g] = nM;
                #pragma unroll
                for (int nt = 0; nt < 4; ++nt) O[nt][g] *= sc_;
            }
            #pragma unroll
            for (int nt = 0; nt < 4; ++nt) {
                #pragma unroll
                for (int g = 0; g < 4; ++g) {
                    int p = (cb << 6) + nt * 16 + col;
                    float w = weightf<SEL>(p, tq[g], mk0[g], mk1[g]);
                    float ev = (w > 0.0f) ? w * expf(sv[nt][g] - M[g]) : 0.0f;
                    l[g] += ev;
                    ps[quad * 4 + g][nt * 16 + col] = ev;
                }
            }
            float4 p0 = *(const float4*)&ps[col][quad * 8];
            float4 p1 = *(const float4*)&ps[col][quad * 8 + 4];
            float4 p2 = *(const float4*)&ps[col][32 + quad * 8];
            float4 p3 = *(const float4*)&ps[col][32 + quad * 8 + 4];
            bf16x8 ap0 = cvt8(p0, p1);
            bf16x8 ap1 = cvt8(p2, p3);
            #pragma unroll
            for (int nt = 0; nt < 4; ++nt) {
                bf16x8 bv0 = *(const bf16x8*)&vt[nt * 16 + col][quad * 8];
                bf16x8 bv1 = *(const bf16x8*)&vt[nt * 16 + col][32 + quad * 8];
                O[nt] = __builtin_amdgcn_mfma_f32_16x16x32_bf16(ap0, bv0, O[nt], 0, 0, 0);
                O[nt] = __builtin_amdgcn_mfma_f32_16x16x32_bf16(ap1, bv1, O[nt], 0, 0, 0);
            }

            if (nxt < 0) break;
            cb = nxt; rem = rem2;
        }
    }
    #pragma unroll
    for (int g = 0; g < 4; ++g) {
        l[g] += __shfl_xor(l[g], 1);
        l[g] += __shfl_xor(l[g], 2);
        l[g] += __shfl_xor(l[g], 4);
        l[g] += __shfl_xor(l[g], 8);
        float inv = 1.0f / l[g];
        #pragma unroll
        for (int nt = 0; nt < 4; ++nt) O[nt][g] *= inv;
    }
}

// ---------------------------------------------------------------------------
// r14 fused attention: grid (64, 4, 2).
//   z=0: f32 cmp phase (scores/softmax/top-8/ocmp — r13 arithmetic verbatim,
//        selection exact, tile-local) + sel flash. z=1: win flash only.
// All contributions atomicAdd onto out (zeroed by hipMemsetAsync) — order-
// free combine, no cmp dispatch, no selmask round-trip.
// LDS phase-carved (40.2 KB): cmp's qf32/chunk/pcmp alias flash's ks/vt/ps.
// ---------------------------------------------------------------------------
__global__ __launch_bounds__(256) void nsa_fused2(
    const float* __restrict__ q, const float* __restrict__ gates_lin,
    const float* __restrict__ ksum, const float* __restrict__ vsum,
    const float* __restrict__ k_slc, const float* __restrict__ v_slc,
    const float* __restrict__ k_win, const float* __restrict__ v_win,
    float* __restrict__ out)
{
    extern __shared__ char sm[];
    // flash-phase carve
    unsigned short (*qs)[TQ][72] = (unsigned short(*)[TQ][72])sm;   // [4][16][72] = 9216
    unsigned short (*ks)[72]     = (unsigned short(*)[72])sm;       // [64][72]    = 9216 (after qs consumed)
    unsigned short (*vt)[88]     = (unsigned short(*)[88])(sm + 9216);   // 11264
    float (*ps)[TQ][76]          = (float(*)[TQ][76])(sm + 20480);       // 19456 -> ends 39936
    // cmp-phase carve (aliases; phase-separated by barriers)
    float (*qf)[TQ][64]          = (float(*)[TQ][64])(sm + 20480);       // 16384
    float (*chk)[66]             = (float(*)[66])sm;                     // 16896 (0..16896 < 20480)
    float (*pc)[TQ][64]          = (float(*)[TQ][64])(sm + 20480);       // 16384 (after qf consumed)
    unsigned int (*selm)[2]      = (unsigned int(*)[2])(sm + 39936);     // 128
    unsigned int* cmaskp         = (unsigned int*)(sm + 40064);

    const int t0 = blockIdx.x * TQ;
    const int k  = blockIdx.y;
    const int br = blockIdx.z;          // 0 = cmp+sel, 1 = win
    const int tid = threadIdx.x, lane = tid & 63, r = tid >> 6;
    const int quad = lane >> 4, col = lane & 15;
    const int hq = r * NKV + k;

    // ---- stage Q bf16, load MFMA A-fragments, then LDS is free ----
    {
        int qrow = lane >> 2, dseg = lane & 3;
        const float* src = q + ((r * NKV + k) * T_LEN + t0 + qrow) * DH + dseg * 16;
        float4 a0 = *(const float4*)src,       a1 = *(const float4*)(src + 4);
        float4 a2 = *(const float4*)(src + 8), a3 = *(const float4*)(src + 12);
        *(bf16x8*)&qs[r][qrow][dseg * 16]     = cvt8(a0, a1);
        *(bf16x8*)&qs[r][qrow][dseg * 16 + 8] = cvt8(a2, a3);
    }
    __syncthreads();
    bf16x8 qf0 = *(const bf16x8*)&qs[r][col][quad * 8];
    bf16x8 qf1 = *(const bf16x8*)&qs[r][col][32 + quad * 8];
    __syncthreads();   // all frag reads done; LDS reusable

    f32x4 O[4];
    const int tmax = t0 + TQ - 1;

    if (br == 0) {
        // ================= cmp phase (f32, selection exact) =================
        // stage q f32 + ksum chunk
        for (int e = tid; e < REP * TQ * 16; e += 256) {       // 1024 float4s
            int rr = e >> 8, rem = e & 255, tt = rem >> 4, d4 = rem & 15;
            *(float4*)&qf[rr][tt][d4 * 4] =
                *(const float4*)(q + ((rr * NKV + k) * T_LEN + t0 + tt) * DH + d4 * 4);
        }
        for (int e = tid; e < 64 * 32; e += 256) {
            int p = e >> 5, d2 = e & 31;
            int nn = (p < NB) ? p : NB - 1;
            *(float2*)&chk[p][d2 * 2] = *(const float2*)(ksum + (nn * NKV + k) * DH + d2 * 2);
        }
        __syncthreads();

        // scores for 16 queries in 4 groups of 4 (r13 cmp arithmetic verbatim)
        float sarr[TQ];
        #pragma unroll
        for (int go = 0; go < 4; ++go) {
            float acc[4] = {0.f, 0.f, 0.f, 0.f};
            #pragma unroll 8
            for (int d2 = 0; d2 < 32; ++d2) {
                float2 cd = *(const float2*)&chk[lane][d2 * 2];
                #pragma unroll
                for (int tt = 0; tt < 4; ++tt) {
                    float2 qd = *(const float2*)&qf[r][go * 4 + tt][d2 * 2];
                    acc[tt] += qd.x * cd.x + qd.y * cd.y;
                }
            }
            #pragma unroll
            for (int tt = 0; tt < 4; ++tt) {
                bool ok = (lane < NB) && ((lane * 16 + 31) <= (t0 + go * 4 + tt));
                sarr[go * 4 + tt] = ok ? acc[tt] * 0.125f : -1e30f;
            }
        }
        // softmax per query (registers + shfl only)
        float pv[TQ];
        #pragma unroll
        for (int tt = 0; tt < TQ; ++tt) {
            float m = sarr[tt];
            for (int off = 32; off; off >>= 1) m = fmaxf(m, __shfl_xor(m, off));
            float e = (lane < NB) ? expf(sarr[tt] - m) : 0.0f;
            float sum = e;
            for (int off = 32; off; off >>= 1) sum += __shfl_xor(sum, off);
            pv[tt] = (lane < NB) ? (e / sum) : 0.0f;
        }
        __syncthreads();   // qf reads + chk(ksum) reads done everywhere
        // write pcmp (overwrites qf region); stage vsum (overwrites chk)
        #pragma unroll
        for (int tt = 0; tt < TQ; ++tt) pc[r][tt][lane] = pv[tt];
        for (int e = tid; e < 64 * 32; e += 256) {
            int p = e >> 5, d2 = e & 31;
            int nn = (p < NB) ? p : NB - 1;
            *(float2*)&chk[p][d2 * 2] = *(const float2*)(vsum + (nn * NKV + k) * DH + d2 * 2);
        }
        __syncthreads();

        // top-8 per query: wave r handles tt = 4r..4r+3 (r13 butterfly verbatim)
        #pragma unroll
        for (int j = 0; j < 4; ++j) {
            int tt = r * 4 + j;
            float imp = (lane < NB)
                ? (pc[0][tt][lane] + pc[1][tt][lane] + pc[2][tt][lane] + pc[3][tt][lane])
                : -1e30f;
            unsigned long long msk = 0ull;
            for (int it = 0; it < TOPN; ++it) {
                float v = imp; int i = lane;
                for (int off = 32; off; off >>= 1) {
                    float ov = __shfl_xor(v, off);
                    int   oi = __shfl_xor(i, off);
                    if (ov > v || (ov == v && oi < i)) { v = ov; i = oi; }
                }
                msk |= 1ull << i;
                if (lane == i) imp = -1e30f;
            }
            if (lane == 0) {
                selm[tt][0] = (unsigned int)(msk & 0xffffffffu);
                selm[tt][1] = (unsigned int)(msk >> 32);
            }
        }

        // ocmp (r13 order) + gated atomic write, 4 groups of 4
        #pragma unroll
        for (int go = 0; go < 4; ++go) {
            float oc[4] = {0.f, 0.f, 0.f, 0.f};
            #pragma unroll 4
            for (int n = 0; n < NB; ++n) {
                float cv = chk[n][lane];
                #pragma unroll
                for (int tt = 0; tt < 4; ++tt)
                    oc[tt] += pc[r][go * 4 + tt][n] * cv;
            }
            #pragma unroll
            for (int tt = 0; tt < 4; ++tt) {
                int t = t0 + go * 4 + tt;
                float o = (t >= 31) ? oc[tt] : 0.0f;
                float g0 = sigmoidf(gates_lin[t * 48 + hq * 3]);
                atomicAdd(&out[(hq * T_LEN + t) * DH + lane], g0 * o);
            }
        }
        __syncthreads();   // pc/chk reads done before flash overwrites

        // sel chunk bitmask (r13 verbatim)
        if (tid < TQ) {
            unsigned long long mk = (unsigned long long)selm[tid][0]
                                  | ((unsigned long long)selm[tid][1] << 32);
            unsigned cm = 0;
            #pragma unroll
            for (int m2 = 0; m2 < 16; ++m2) {
                unsigned nib = (unsigned)((mk >> (4 * m2)) & 0xFull);
                if (nib) cm |= 1u << m2;
                if (nib & 8u) cm |= 1u << (m2 + 1);
            }
            cm |= __shfl_xor(cm, 1); cm |= __shfl_xor(cm, 2);
            cm |= __shfl_xor(cm, 4); cm |= __shfl_xor(cm, 8);
            if (tid == 0) *cmaskp = cm;
        }
        __syncthreads();

        // ================= sel flash =================
        flash_branch<true>(k_slc, v_slc, k, t0, 0, tmax >> 6, *cmaskp,
                           tid, quad, col, qf0, qf1, ks, vt, ps[r], selm, O);
    } else {
        // ================= win flash =================
        int wlo = t0 - 255; if (wlo < 0) wlo = 0;
        flash_branch<false>(k_win, v_win, k, t0, wlo >> 6, tmax >> 6, 0xFFFFFFFFu,
                            tid, quad, col, qf0, qf1, ks, vt, ps[r], selm, O);
    }

    // gated atomic accumulate of the flash branch
    #pragma unroll
    for (int g = 0; g < 4; ++g) {
        int tq = t0 + quad * 4 + g;
        float gg = sigmoidf(gates_lin[tq * 48 + hq * 3 + 1 + br]);
        #pragma unroll
        for (int nt = 0; nt < 4; ++nt) {
            int d = nt * 16 + col;
            atomicAdd(&out[(hq * T_LEN + tq) * DH + d], gg * O[nt][g]);
        }
    }
}

extern "C" void kernel_launch(void* const* d_in, const int* in_sizes, int n_in,
                              void* d_out, int out_size, void* d_ws, size_t ws_size,
                              hipStream_t stream) {
    const float* x         = (const float*)d_in[0];
    const float* q         = (const float*)d_in[1];
    const float* gate_w    = (const float*)d_in[2];
    const float* gate_b    = (const float*)d_in[3];
    const float* wk_cmp    = (const float*)d_in[4];
    const float* wv_cmp    = (const float*)d_in[5];
    const float* wk_slc    = (const float*)d_in[6];
    const float* wv_slc    = (const float*)d_in[7];
    const float* wk_win    = (const float*)d_in[8];
    const float* wv_win    = (const float*)d_in[9];
    const float* block_pos = (const float*)d_in[10];
    const float* ck1_w     = (const float*)d_in[11];
    const float* ck1_b     = (const float*)d_in[12];
    const float* ck2_w     = (const float*)d_in[13];
    const float* ck2_b     = (const float*)d_in[14];
    const float* cv1_w     = (const float*)d_in[15];
    const float* cv1_b     = (const float*)d_in[16];
    const float* cv2_w     = (const float*)d_in[17];
    const float* cv2_b     = (const float*)d_in[18];
    float* out = (float*)d_out;

    float* ws = (float*)d_ws;
    float* gates_lin = ws;                         // 1024*48
    float* k_cmp = gates_lin + T_LEN * 48;         // 1024*256 each
    float* v_cmp = k_cmp + T_LEN * KVD;
    float* k_slc = v_cmp + T_LEN * KVD;
    float* v_slc = k_slc + T_LEN * KVD;
    float* k_win = v_slc + T_LEN * KVD;
    float* v_win = k_win + T_LEN * KVD;
    float* ksum  = v_win + T_LEN * KVD;            // 63*4*64 each
    float* vsum  = ksum + NB * KVD;

    dim3 blk(256);
    hipMemsetAsync(out, 0, (size_t)out_size * sizeof(float), stream);
    size_t smem_proj = 2 * 32 * 68 * sizeof(float);
    proj_all<<<dim3(25, 16), blk, smem_proj, stream>>>(
        x, gate_w, gate_b, wk_cmp, wv_cmp, wk_slc, wv_slc, wk_win, wv_win,
        gates_lin, k_cmp, v_cmp, k_slc, v_slc, k_win, v_win);
    nsa_summarize<<<dim3(16, NKV, 2), blk, 0, stream>>>(
        k_cmp, v_cmp, block_pos,
        ck1_w, ck1_b, ck2_w, ck2_b, cv1_w, cv1_b, cv2_w, cv2_b,
        ksum, vsum);
    size_t smem_fused = 40192;
    nsa_fused2<<<dim3(T_LEN / TQ, NKV, 2), blk, smem_fused, stream>>>(
        q, gates_lin, ksum, vsum, k_slc, v_slc, k_win, v_win, out);
}

// Round 15
// 246.824 us; speedup vs baseline: 1.0365x; 1.0365x over previous
//
#include <hip/hip_runtime.h>
#include <hip/hip_bf16.h>
#include <math.h>

#define T_LEN 1024
#define D_MODEL 1024
#define NKV 4
#define REP 4
#define DH 64
#define NB 63
#define TOPN 8
#define KVD 256        // NKV*DH
#define LDIM2 1328     // virtual concatenated width without k_cmp
#define TQ 16          // query tile for flash
#define T4 4           // query tile for cmp
#define SGN 4          // n-group for summarize

typedef __attribute__((ext_vector_type(8))) short bf16x8;
typedef __attribute__((ext_vector_type(4))) float f32x4;

__device__ __forceinline__ float gelu_exact(float x) {
    return 0.5f * x * (1.0f + erff(x * 0.70710678118654752f));
}
__device__ __forceinline__ float sigmoidf(float x) {
    return 1.0f / (1.0f + expf(-x));
}
__device__ __forceinline__ bf16x8 cvt8(float4 a0, float4 a1) {
    union { __hip_bfloat162 v; short2 s; } u0, u1, u2, u3;
    u0.v = __float22bfloat162_rn(make_float2(a0.x, a0.y));
    u1.v = __float22bfloat162_rn(make_float2(a0.z, a0.w));
    u2.v = __float22bfloat162_rn(make_float2(a1.x, a1.y));
    u3.v = __float22bfloat162_rn(make_float2(a1.z, a1.w));
    bf16x8 r;
    r[0] = u0.s.x; r[1] = u0.s.y; r[2] = u1.s.x; r[3] = u1.s.y;
    r[4] = u2.s.x; r[5] = u2.s.y; r[6] = u3.s.x; r[7] = u3.s.y;
    return r;
}

// ---------------------------------------------------------------------------
// Merged projection dispatch, grid (25,16), dynamic LDS 17408 B (r13 proven).
// ---------------------------------------------------------------------------
__global__ __launch_bounds__(256) void proj_all(
    const float* __restrict__ x,
    const float* __restrict__ gate_w, const float* __restrict__ gate_b,
    const float* __restrict__ wk_cmp, const float* __restrict__ wv_cmp,
    const float* __restrict__ wk_slc, const float* __restrict__ wv_slc,
    const float* __restrict__ wk_win, const float* __restrict__ wv_win,
    float* __restrict__ gates_lin, float* __restrict__ k_cmp,
    float* __restrict__ v_cmp,
    float* __restrict__ k_slc, float* __restrict__ v_slc,
    float* __restrict__ k_win, float* __restrict__ v_win)
{
    extern __shared__ char smem[];
    const int tid = threadIdx.x;
    const int m0 = blockIdx.y * 64;

    if (blockIdx.x < 21) {
        typedef unsigned short row40[40];
        row40* As = (row40*)smem;
        row40* Bs = (row40*)(smem + 64 * 40 * sizeof(unsigned short));
        const int lane = tid & 63;
        const int w = tid >> 6;
        const int n0 = blockIdx.x * 64;

        const int srow = tid >> 2;
        const int sseg = tid & 3;
        const float* ga = x + (m0 + srow) * D_MODEL + sseg * 8;
        const float* gb;
        {
            int nn = n0 + srow;
            if (nn < 48)        gb = gate_w + nn * D_MODEL;
            else if (nn < 304)  gb = wv_cmp + (nn - 48) * D_MODEL;
            else if (nn < 560)  gb = wk_slc + (nn - 304) * D_MODEL;
            else if (nn < 816)  gb = wv_slc + (nn - 560) * D_MODEL;
            else if (nn < 1072) gb = wk_win + (nn - 816) * D_MODEL;
            else if (nn < 1328) gb = wv_win + (nn - 1072) * D_MODEL;
            else                gb = gate_w;
            gb += sseg * 8;
        }

        f32x4 acc[4] = {};
        const int arow = (w << 4) + (lane & 15);
        const int kk8  = (lane >> 4) * 8;

        float4 a0 = *(const float4*)(ga);
        float4 a1 = *(const float4*)(ga + 4);
        float4 b0 = *(const float4*)(gb);
        float4 b1 = *(const float4*)(gb + 4);

        for (int k0 = 0; k0 < D_MODEL; k0 += 32) {
            bf16x8 ap = cvt8(a0, a1);
            bf16x8 bp = cvt8(b0, b1);
            __syncthreads();
            *(bf16x8*)&As[srow][sseg * 8] = ap;
            *(bf16x8*)&Bs[srow][sseg * 8] = bp;
            __syncthreads();
            if (k0 + 32 < D_MODEL) {
                a0 = *(const float4*)(ga + k0 + 32);
                a1 = *(const float4*)(ga + k0 + 36);
                b0 = *(const float4*)(gb + k0 + 32);
                b1 = *(const float4*)(gb + k0 + 36);
            }
            bf16x8 af = *(bf16x8*)&As[arow][kk8];
            #pragma unroll
            for (int j = 0; j < 4; ++j) {
                bf16x8 bfr = *(bf16x8*)&Bs[j * 16 + (lane & 15)][kk8];
                acc[j] = __builtin_amdgcn_mfma_f32_16x16x32_bf16(af, bfr, acc[j], 0, 0, 0);
            }
        }

        #pragma unroll
        for (int j = 0; j < 4; ++j) {
            int col = n0 + j * 16 + (lane & 15);
            if (col >= LDIM2) continue;
            int rbase = m0 + (w << 4) + (lane >> 4) * 4;
            float* dst; int cc; int stride = 256; float badd = 0.0f;
            if (col < 48)        { dst = gates_lin; cc = col;        stride = 48; badd = gate_b[col]; }
            else if (col < 304)  { dst = v_cmp;     cc = col - 48;   }
            else if (col < 560)  { dst = k_slc;     cc = col - 304;  }
            else if (col < 816)  { dst = v_slc;     cc = col - 560;  }
            else if (col < 1072) { dst = k_win;     cc = col - 816;  }
            else                 { dst = v_win;     cc = col - 1072; }
            #pragma unroll
            for (int rg = 0; rg < 4; ++rg)
                dst[(rbase + rg) * stride + cc] = acc[j][rg] + badd;
        }
    } else {
        typedef float row68[68];
        row68* As = (row68*)smem;
        row68* Bs = (row68*)(smem + 32 * 68 * sizeof(float));
        const int tx = tid & 15, ty = tid >> 4;
        const int n0 = (blockIdx.x - 21) * 64;
        const int srow = tid >> 2, sseg = tid & 3;
        const float* ga = x + (m0 + srow) * D_MODEL + sseg * 8;
        const float* gb = wk_cmp + (n0 + srow) * D_MODEL + sseg * 8;

        float acc[4][4] = {};
        float4 a0 = *(const float4*)(ga);
        float4 a1 = *(const float4*)(ga + 4);
        float4 b0 = *(const float4*)(gb);
        float4 b1 = *(const float4*)(gb + 4);

        for (int k0 = 0; k0 < D_MODEL; k0 += 32) {
            __syncthreads();
            As[sseg*8+0][srow]=a0.x; As[sseg*8+1][srow]=a0.y; As[sseg*8+2][srow]=a0.z; As[sseg*8+3][srow]=a0.w;
            As[sseg*8+4][srow]=a1.x; As[sseg*8+5][srow]=a1.y; As[sseg*8+6][srow]=a1.z; As[sseg*8+7][srow]=a1.w;
            Bs[sseg*8+0][srow]=b0.x; Bs[sseg*8+1][srow]=b0.y; Bs[sseg*8+2][srow]=b0.z; Bs[sseg*8+3][srow]=b0.w;
            Bs[sseg*8+4][srow]=b1.x; Bs[sseg*8+5][srow]=b1.y; Bs[sseg*8+6][srow]=b1.z; Bs[sseg*8+7][srow]=b1.w;
            __syncthreads();
            if (k0 + 32 < D_MODEL) {
                a0 = *(const float4*)(ga + k0 + 32);
                a1 = *(const float4*)(ga + k0 + 36);
                b0 = *(const float4*)(gb + k0 + 32);
                b1 = *(const float4*)(gb + k0 + 36);
            }
            #pragma unroll
            for (int kk = 0; kk < 32; ++kk) {
                float4 a4 = *(const float4*)&As[kk][ty * 4];
                float4 b4 = *(const float4*)&Bs[kk][tx * 4];
                acc[0][0] += a4.x*b4.x; acc[0][1] += a4.x*b4.y; acc[0][2] += a4.x*b4.z; acc[0][3] += a4.x*b4.w;
                acc[1][0] += a4.y*b4.x; acc[1][1] += a4.y*b4.y; acc[1][2] += a4.y*b4.z; acc[1][3] += a4.y*b4.w;
                acc[2][0] += a4.z*b4.x; acc[2][1] += a4.z*b4.y; acc[2][2] += a4.z*b4.z; acc[2][3] += a4.z*b4.w;
                acc[3][0] += a4.w*b4.x; acc[3][1] += a4.w*b4.y; acc[3][2] += a4.w*b4.z; acc[3][3] += a4.w*b4.w;
            }
        }
        #pragma unroll
        for (int i = 0; i < 4; ++i) {
            int mm = m0 + ty * 4 + i;
            #pragma unroll
            for (int j = 0; j < 4; ++j)
                k_cmp[mm * KVD + n0 + tx * 4 + j] = acc[i][j];
        }
    }
}

// ---------------------------------------------------------------------------
// Block summaries, 4-wide n-tiling (r13 proven). grid (16, 4, 2).
// ---------------------------------------------------------------------------
__global__ __launch_bounds__(256) void nsa_summarize(
    const float* __restrict__ k_cmp, const float* __restrict__ v_cmp,
    const float* __restrict__ block_pos,
    const float* __restrict__ ck1_w, const float* __restrict__ ck1_b,
    const float* __restrict__ ck2_w, const float* __restrict__ ck2_b,
    const float* __restrict__ cv1_w, const float* __restrict__ cv1_b,
    const float* __restrict__ cv2_w, const float* __restrict__ cv2_b,
    float* __restrict__ ksum, float* __restrict__ vsum)
{
    const int ng = blockIdx.x, k = blockIdx.y, which = blockIdx.z;
    const int n0 = ng * SGN;
    const float* src = which ? v_cmp : k_cmp;
    const float* w1  = which ? cv1_w : ck1_w;
    const float* b1  = which ? cv1_b : ck1_b;
    const float* w2  = which ? cv2_w : ck2_w;
    const float* b2  = which ? cv2_b : ck2_b;
    float* dst       = which ? vsum  : ksum;

    __shared__ float flat[SGN][4 * 516];
    __shared__ float hidden[SGN][DH];
    const int tid = threadIdx.x;

    #pragma unroll
    for (int j = 0; j < SGN; ++j) {
        int n = n0 + j; if (n >= NB) n = NB - 1;
        int start = n * 16;
        for (int e = tid; e < 512; e += 256) {
            int p = e >> 4, d4 = e & 15;
            float4 s = *(const float4*)(src + ((start + p) * NKV + k) * DH + d4 * 4);
            float4 bp = *(const float4*)(block_pos + p * DH + d4 * 4);
            float4 r; r.x = s.x + bp.x; r.y = s.y + bp.y; r.z = s.z + bp.z; r.w = s.w + bp.w;
            *(float4*)&flat[j][(p >> 3) * 516 + (p & 7) * 64 + d4 * 4] = r;
        }
    }
    __syncthreads();
    {
        int h = tid >> 2, part = tid & 3;
        const float* wr = w1 + h * 2048 + part * 512;
        float s[SGN] = {0.f, 0.f, 0.f, 0.f};
        for (int jj = 0; jj < 512; jj += 4) {
            float4 b = *(const float4*)(wr + jj);
            #pragma unroll
            for (int j = 0; j < SGN; ++j) {
                float4 a = *(const float4*)&flat[j][part * 516 + jj];
                s[j] += a.x * b.x + a.y * b.y + a.z * b.z + a.w * b.w;
            }
        }
        #pragma unroll
        for (int j = 0; j < SGN; ++j) {
            float v = s[j];
            v += __shfl_xor(v, 1);
            v += __shfl_xor(v, 2);
            if (part == 0) hidden[j][h] = gelu_exact(v + b1[h]);
        }
    }
    __syncthreads();
    {
        int dh = tid >> 2, part = tid & 3;
        const float* wr = w2 + dh * 64 + part * 16;
        float s[SGN] = {0.f, 0.f, 0.f, 0.f};
        #pragma unroll
        for (int hh = 0; hh < 16; ++hh) {
            float b = wr[hh];
            #pragma unroll
            for (int j = 0; j < SGN; ++j)
                s[j] += hidden[j][part * 16 + hh] * b;
        }
        #pragma unroll
        for (int j = 0; j < SGN; ++j) {
            float v = s[j];
            v += __shfl_xor(v, 1);
            v += __shfl_xor(v, 2);
            if (part == 0 && (n0 + j) < NB)
                dst[((n0 + j) * NKV + k) * DH + dh] = v + b2[dh];
        }
    }
}

// ---------------------------------------------------------------------------
// Flash machinery (r13 proven verbatim).
// ---------------------------------------------------------------------------
template<bool SEL>
__device__ __forceinline__ float weightf(int p, int tq, unsigned mk0, unsigned mk1) {
    if (SEL) {
        int b = p >> 4;
        unsigned c = (b < 32) ? ((mk0 >> b) & 1u) : ((mk1 >> (b - 32)) & 1u);
        int b2 = b - 1;
        if (b2 >= 0)
            c += (b2 < 32) ? ((mk0 >> b2) & 1u) : ((mk1 >> (b2 - 32)) & 1u);
        return (p <= tq) ? (float)c : 0.0f;
    } else {
        return (p <= tq && p > tq - 256) ? 1.0f : 0.0f;
    }
}

struct KRegs { float4 a0, a1, a2, a3; };
struct VRegs { float4 x0, x1, y0, y1; };

__device__ __forceinline__ KRegs load_k_regs(const float* kptr, int k, int cb, int tid) {
    int row = tid >> 2, dseg = tid & 3;
    const float* src = kptr + (((cb << 6) + row) * NKV + k) * DH + dseg * 16;
    KRegs r;
    r.a0 = *(const float4*)(src);
    r.a1 = *(const float4*)(src + 4);
    r.a2 = *(const float4*)(src + 8);
    r.a3 = *(const float4*)(src + 12);
    return r;
}
__device__ __forceinline__ void write_k(const KRegs& r, int tid, unsigned short (*ks)[72]) {
    int row = tid >> 2, dseg = tid & 3;
    *(bf16x8*)&ks[row][dseg * 16]     = cvt8(r.a0, r.a1);
    *(bf16x8*)&ks[row][dseg * 16 + 8] = cvt8(r.a2, r.a3);
}
__device__ __forceinline__ VRegs load_v_regs(const float* vptr, int k, int cb, int tid) {
    int l = tid & 63, wv = tid >> 6;
    int dbase = wv * 16 + ((l >> 5) << 3);
    int pp = (l & 31) * 2;
    const float* v0 = vptr + (((cb << 6) + pp) * NKV + k) * DH + dbase;
    const float* v1 = v0 + NKV * DH;
    VRegs r;
    r.x0 = *(const float4*)v0; r.x1 = *(const float4*)(v0 + 4);
    r.y0 = *(const float4*)v1; r.y1 = *(const float4*)(v1 + 4);
    return r;
}
__device__ __forceinline__ void write_v(const VRegs& r, int tid, unsigned short (*vt)[88]) {
    int l = tid & 63, wv = tid >> 6;
    int dbase = wv * 16 + ((l >> 5) << 3);
    int pp = (l & 31) * 2;
    union { __hip_bfloat162 v; unsigned u; } t_;
    t_.v = __float22bfloat162_rn(make_float2(r.x0.x, r.y0.x)); *(unsigned*)&vt[dbase + 0][pp] = t_.u;
    t_.v = __float22bfloat162_rn(make_float2(r.x0.y, r.y0.y)); *(unsigned*)&vt[dbase + 1][pp] = t_.u;
    t_.v = __float22bfloat162_rn(make_float2(r.x0.z, r.y0.z)); *(unsigned*)&vt[dbase + 2][pp] = t_.u;
    t_.v = __float22bfloat162_rn(make_float2(r.x0.w, r.y0.w)); *(unsigned*)&vt[dbase + 3][pp] = t_.u;
    t_.v = __float22bfloat162_rn(make_float2(r.x1.x, r.y1.x)); *(unsigned*)&vt[dbase + 4][pp] = t_.u;
    t_.v = __float22bfloat162_rn(make_float2(r.x1.y, r.y1.y)); *(unsigned*)&vt[dbase + 5][pp] = t_.u;
    t_.v = __float22bfloat162_rn(make_float2(r.x1.z, r.y1.z)); *(unsigned*)&vt[dbase + 6][pp] = t_.u;
    t_.v = __float22bfloat162_rn(make_float2(r.x1.w, r.y1.w)); *(unsigned*)&vt[dbase + 7][pp] = t_.u;
}

template<bool SEL>
__device__ __forceinline__ void flash_branch(
    const float* kptr, const float* vptr, int k, int t0, int c0, int c1,
    unsigned cmask,
    int tid, int quad, int col,
    bf16x8 qf0, bf16x8 qf1,
    unsigned short (*ks)[72], unsigned short (*vt)[88], float (*ps)[76],
    const unsigned int (*selm)[2],
    f32x4 (&O)[4])
{
    unsigned mk0[4] = {0,0,0,0}, mk1[4] = {0,0,0,0};
    int tq[4];
    #pragma unroll
    for (int g = 0; g < 4; ++g) {
        int row = quad * 4 + g;
        tq[g] = t0 + row;
        if (SEL) { mk0[g] = selm[row][0]; mk1[g] = selm[row][1]; }
    }

    float M[4] = {-1e30f, -1e30f, -1e30f, -1e30f};
    float l[4] = {0.f, 0.f, 0.f, 0.f};
    f32x4 z = {0.f, 0.f, 0.f, 0.f};
    O[0] = z; O[1] = z; O[2] = z; O[3] = z;

    unsigned rem = cmask & ((2u << c1) - 1u);
    rem = (rem >> c0) << c0;

    if (rem) {
        int cb = __builtin_ctz(rem);
        KRegs kr = load_k_regs(kptr, k, cb, tid);
        VRegs vr = load_v_regs(vptr, k, cb, tid);
        while (true) {
            unsigned rem2 = rem & (rem - 1);
            int nxt = rem2 ? __builtin_ctz(rem2) : -1;
            __syncthreads();
            write_k(kr, tid, ks);
            write_v(vr, tid, vt);
            __syncthreads();
            if (nxt >= 0) {
                kr = load_k_regs(kptr, k, nxt, tid);
                vr = load_v_regs(vptr, k, nxt, tid);
            }

            float sv[4][4];
            #pragma unroll
            for (int nt = 0; nt < 4; ++nt) {
                bf16x8 b0 = *(const bf16x8*)&ks[nt * 16 + col][quad * 8];
                bf16x8 b1 = *(const bf16x8*)&ks[nt * 16 + col][32 + quad * 8];
                f32x4 sc = {0.f, 0.f, 0.f, 0.f};
                sc = __builtin_amdgcn_mfma_f32_16x16x32_bf16(qf0, b0, sc, 0, 0, 0);
                sc = __builtin_amdgcn_mfma_f32_16x16x32_bf16(qf1, b1, sc, 0, 0, 0);
                #pragma unroll
                for (int g = 0; g < 4; ++g) sv[nt][g] = sc[g] * 0.125f;
            }
            #pragma unroll
            for (int g = 0; g < 4; ++g) {
                float cm = -1e30f;
                #pragma unroll
                for (int nt = 0; nt < 4; ++nt) {
                    int p = (cb << 6) + nt * 16 + col;
                    float w = weightf<SEL>(p, tq[g], mk0[g], mk1[g]);
                    if (w > 0.0f) cm = fmaxf(cm, sv[nt][g]);
                }
                cm = fmaxf(cm, __shfl_xor(cm, 1));
                cm = fmaxf(cm, __shfl_xor(cm, 2));
                cm = fmaxf(cm, __shfl_xor(cm, 4));
                cm = fmaxf(cm, __shfl_xor(cm, 8));
                float nM = fmaxf(M[g], cm);
                float sc_ = expf(M[g] - nM);
                l[g] *= sc_;
                M[g] = nM;
                #pragma unroll
                for (int nt = 0; nt < 4; ++nt) O[nt][g] *= sc_;
            }
            #pragma unroll
            for (int nt = 0; nt < 4; ++nt) {
                #pragma unroll
                for (int g = 0; g < 4; ++g) {
                    int p = (cb << 6) + nt * 16 + col;
                    float w = weightf<SEL>(p, tq[g], mk0[g], mk1[g]);
                    float ev = (w > 0.0f) ? w * expf(sv[nt][g] - M[g]) : 0.0f;
                    l[g] += ev;
                    ps[quad * 4 + g][nt * 16 + col] = ev;
                }
            }
            float4 p0 = *(const float4*)&ps[col][quad * 8];
            float4 p1 = *(const float4*)&ps[col][quad * 8 + 4];
            float4 p2 = *(const float4*)&ps[col][32 + quad * 8];
            float4 p3 = *(const float4*)&ps[col][32 + quad * 8 + 4];
            bf16x8 ap0 = cvt8(p0, p1);
            bf16x8 ap1 = cvt8(p2, p3);
            #pragma unroll
            for (int nt = 0; nt < 4; ++nt) {
                bf16x8 bv0 = *(const bf16x8*)&vt[nt * 16 + col][quad * 8];
                bf16x8 bv1 = *(const bf16x8*)&vt[nt * 16 + col][32 + quad * 8];
                O[nt] = __builtin_amdgcn_mfma_f32_16x16x32_bf16(ap0, bv0, O[nt], 0, 0, 0);
                O[nt] = __builtin_amdgcn_mfma_f32_16x16x32_bf16(ap1, bv1, O[nt], 0, 0, 0);
            }

            if (nxt < 0) break;
            cb = nxt; rem = rem2;
        }
    }
    #pragma unroll
    for (int g = 0; g < 4; ++g) {
        l[g] += __shfl_xor(l[g], 1);
        l[g] += __shfl_xor(l[g], 2);
        l[g] += __shfl_xor(l[g], 4);
        l[g] += __shfl_xor(l[g], 8);
        float inv = 1.0f / l[g];
        #pragma unroll
        for (int nt = 0; nt < 4; ++nt) O[nt][g] *= inv;
    }
}

// stage Q bf16 tile + extract MFMA A-fragments; sm region free afterwards
__device__ __forceinline__ void stage_q_frags(
    const float* q, int k, int t0, int tid, char* sm,
    bf16x8& qf0, bf16x8& qf1)
{
    const int lane = tid & 63, r = tid >> 6;
    const int quad = lane >> 4, col = lane & 15;
    unsigned short (*qs)[TQ][72] = (unsigned short(*)[TQ][72])sm;
    {
        int qrow = lane >> 2, dseg = lane & 3;
        const float* src = q + ((r * NKV + k) * T_LEN + t0 + qrow) * DH + dseg * 16;
        float4 a0 = *(const float4*)src,       a1 = *(const float4*)(src + 4);
        float4 a2 = *(const float4*)(src + 8), a3 = *(const float4*)(src + 12);
        *(bf16x8*)&qs[r][qrow][dseg * 16]     = cvt8(a0, a1);
        *(bf16x8*)&qs[r][qrow][dseg * 16 + 8] = cvt8(a2, a3);
    }
    __syncthreads();
    qf0 = *(const bf16x8*)&qs[r][col][quad * 8];
    qf1 = *(const bf16x8*)&qs[r][col][32 + quad * 8];
    __syncthreads();
}

// ---------------------------------------------------------------------------
// r15: cmp ∥ win merged (INDEPENDENT work — r14 mistakenly fused the
// dependency chain cmp→sel). grid (320, 4): bx<256 cmp (r13 verbatim,
// atomicAdd epilogue), bx>=256 win flash tile. Dynamic LDS 40192 B.
// ---------------------------------------------------------------------------
__global__ __launch_bounds__(256) void nsa_cmp_win(
    const float* __restrict__ q, const float* __restrict__ gates_lin,
    const float* __restrict__ ksum, const float* __restrict__ vsum,
    const float* __restrict__ k_win, const float* __restrict__ v_win,
    float* __restrict__ out, unsigned int* __restrict__ selmask_ws)
{
    extern __shared__ char sm[];
    const int k = blockIdx.y;
    const int tid = threadIdx.x, lane = tid & 63, r = tid >> 6;

    if (blockIdx.x < 256) {
        // ================= cmp path (r13 nsa_cmp verbatim) =================
        float (*q_s)[T4][DH]   = (float(*)[T4][DH])sm;              // 4096
        float (*chunk)[66]     = (float(*)[66])(sm + 4096);         // 16896
        float (*p_cmp_s)[T4][64] = (float(*)[T4][64])(sm + 20992);  // 4096
        const int t0 = blockIdx.x * T4;

        #pragma unroll
        for (int tt = 0; tt < T4; ++tt)
            q_s[r][tt][lane] = q[((r * NKV + k) * T_LEN + t0 + tt) * DH + lane];
        for (int e = tid; e < 64 * 32; e += 256) {
            int p = e >> 5, d2 = e & 31;
            int nn = (p < NB) ? p : NB - 1;
            *(float2*)&chunk[p][d2 * 2] = *(const float2*)(ksum + (nn * NKV + k) * DH + d2 * 2);
        }
        __syncthreads();

        float sarr[T4];
        {
            float acc[T4] = {0.f, 0.f, 0.f, 0.f};
            #pragma unroll 8
            for (int d2 = 0; d2 < 32; ++d2) {
                float2 cd = *(const float2*)&chunk[lane][d2 * 2];
                #pragma unroll
                for (int tt = 0; tt < T4; ++tt) {
                    float2 qd = *(const float2*)&q_s[r][tt][d2 * 2];
                    acc[tt] += qd.x * cd.x + qd.y * cd.y;
                }
            }
            #pragma unroll
            for (int tt = 0; tt < T4; ++tt) {
                bool ok = (lane < NB) && ((lane * 16 + 31) <= (t0 + tt));
                sarr[tt] = ok ? acc[tt] * 0.125f : -1e30f;
            }
        }
        #pragma unroll
        for (int tt = 0; tt < T4; ++tt) {
            float m = sarr[tt];
            for (int off = 32; off; off >>= 1) m = fmaxf(m, __shfl_xor(m, off));
            float e = (lane < NB) ? expf(sarr[tt] - m) : 0.0f;
            float sum = e;
            for (int off = 32; off; off >>= 1) sum += __shfl_xor(sum, off);
            p_cmp_s[r][tt][lane] = (lane < NB) ? (e / sum) : 0.0f;
        }
        __syncthreads();

        for (int e2 = tid; e2 < 64 * 32; e2 += 256) {
            int p = e2 >> 5, d2 = e2 & 31;
            int nn = (p < NB) ? p : NB - 1;
            *(float2*)&chunk[p][d2 * 2] = *(const float2*)(vsum + (nn * NKV + k) * DH + d2 * 2);
        }
        {
            float imp = (lane < NB)
                ? (p_cmp_s[0][r][lane] + p_cmp_s[1][r][lane] + p_cmp_s[2][r][lane] + p_cmp_s[3][r][lane])
                : -1e30f;
            unsigned long long msk = 0ull;
            for (int it = 0; it < TOPN; ++it) {
                float v = imp; int i = lane;
                for (int off = 32; off; off >>= 1) {
                    float ov = __shfl_xor(v, off);
                    int   oi = __shfl_xor(i, off);
                    if (ov > v || (ov == v && oi < i)) { v = ov; i = oi; }
                }
                msk |= 1ull << i;
                if (lane == i) imp = -1e30f;
            }
            if (lane == 0) {
                selmask_ws[(k * T_LEN + t0 + r) * 2 + 0] = (unsigned int)(msk & 0xffffffffu);
                selmask_ws[(k * T_LEN + t0 + r) * 2 + 1] = (unsigned int)(msk >> 32);
            }
        }
        __syncthreads();

        float oc[T4] = {0.f, 0.f, 0.f, 0.f};
        #pragma unroll 4
        for (int n = 0; n < NB; ++n) {
            float cv = chunk[n][lane];
            #pragma unroll
            for (int tt = 0; tt < T4; ++tt)
                oc[tt] += p_cmp_s[r][tt][n] * cv;
        }
        const int hq = r * NKV + k;
        #pragma unroll
        for (int tt = 0; tt < T4; ++tt) {
            int t = t0 + tt;
            float o = (t >= 31) ? oc[tt] : 0.0f;
            float g0 = sigmoidf(gates_lin[t * 48 + hq * 3]);
            atomicAdd(&out[(hq * T_LEN + t) * DH + lane], g0 * o);
        }
    } else {
        // ================= win flash (r13 body; qs aliased onto ks) ========
        unsigned short (*ks)[72] = (unsigned short(*)[72])sm;           // 9216
        unsigned short (*vt)[88] = (unsigned short(*)[88])(sm + 9216);  // 11264
        float (*ps)[TQ][76]      = (float(*)[TQ][76])(sm + 20480);      // 19456
        const int t0 = (blockIdx.x - 256) * TQ;
        const int quad = lane >> 4, col = lane & 15;

        bf16x8 qf0, qf1;
        stage_q_frags(q, k, t0, tid, sm, qf0, qf1);

        const int tmax = t0 + TQ - 1;
        int wlo = t0 - 255; if (wlo < 0) wlo = 0;
        f32x4 O[4];
        flash_branch<false>(k_win, v_win, k, t0, wlo >> 6, tmax >> 6, 0xFFFFFFFFu,
                            tid, quad, col, qf0, qf1, ks, vt, ps[r],
                            (const unsigned int(*)[2])selmask_ws, O);

        const int hq = r * NKV + k;
        #pragma unroll
        for (int g = 0; g < 4; ++g) {
            int tq = t0 + quad * 4 + g;
            float gg = sigmoidf(gates_lin[tq * 48 + hq * 3 + 2]);
            #pragma unroll
            for (int nt = 0; nt < 4; ++nt) {
                int d = nt * 16 + col;
                atomicAdd(&out[(hq * T_LEN + tq) * DH + d], gg * O[nt][g]);
            }
        }
    }
}

// ---------------------------------------------------------------------------
// r15 sel flash: grid (64, 4). Reads selmask, chunk-skip walk, atomicAdd.
// Dynamic LDS 40192 B (qs aliased onto ks).
// ---------------------------------------------------------------------------
__global__ __launch_bounds__(256) void nsa_sel(
    const float* __restrict__ q, const float* __restrict__ gates_lin,
    const float* __restrict__ k_slc, const float* __restrict__ v_slc,
    const unsigned int* __restrict__ selmask_ws,
    float* __restrict__ out)
{
    extern __shared__ char sm[];
    unsigned short (*ks)[72] = (unsigned short(*)[72])sm;
    unsigned short (*vt)[88] = (unsigned short(*)[88])(sm + 9216);
    float (*ps)[TQ][76]      = (float(*)[TQ][76])(sm + 20480);
    unsigned int (*selm)[2]  = (unsigned int(*)[2])(sm + 39936);
    unsigned int* cmaskp     = (unsigned int*)(sm + 40064);

    const int t0 = blockIdx.x * TQ;
    const int k  = blockIdx.y;
    const int tid = threadIdx.x, lane = tid & 63, r = tid >> 6;
    const int quad = lane >> 4, col = lane & 15;

    if (tid < TQ) {
        selm[tid][0] = selmask_ws[(k * T_LEN + t0 + tid) * 2 + 0];
        selm[tid][1] = selmask_ws[(k * T_LEN + t0 + tid) * 2 + 1];
    }
    // chunk bitmask (uses selm; must complete before qs staging overwrites sm? —
    // selm lives at 39936, outside ks/vt regions; qs occupies 0..9216. Safe.)
    __syncthreads();
    if (tid < TQ) {
        unsigned long long mk = (unsigned long long)selm[tid][0]
                              | ((unsigned long long)selm[tid][1] << 32);
        unsigned cm = 0;
        #pragma unroll
        for (int m2 = 0; m2 < 16; ++m2) {
            unsigned nib = (unsigned)((mk >> (4 * m2)) & 0xFull);
            if (nib) cm |= 1u << m2;
            if (nib & 8u) cm |= 1u << (m2 + 1);
        }
        cm |= __shfl_xor(cm, 1); cm |= __shfl_xor(cm, 2);
        cm |= __shfl_xor(cm, 4); cm |= __shfl_xor(cm, 8);
        if (tid == 0) *cmaskp = cm;
    }
    __syncthreads();
    unsigned cmask = *cmaskp;

    bf16x8 qf0, qf1;
    stage_q_frags(q, k, t0, tid, sm, qf0, qf1);

    const int tmax = t0 + TQ - 1;
    f32x4 O[4];
    flash_branch<true>(k_slc, v_slc, k, t0, 0, tmax >> 6, cmask,
                       tid, quad, col, qf0, qf1, ks, vt, ps[r], selm, O);

    const int hq = r * NKV + k;
    #pragma unroll
    for (int g = 0; g < 4; ++g) {
        int tq = t0 + quad * 4 + g;
        float gg = sigmoidf(gates_lin[tq * 48 + hq * 3 + 1]);
        #pragma unroll
        for (int nt = 0; nt < 4; ++nt) {
            int d = nt * 16 + col;
            atomicAdd(&out[(hq * T_LEN + tq) * DH + d], gg * O[nt][g]);
        }
    }
}

extern "C" void kernel_launch(void* const* d_in, const int* in_sizes, int n_in,
                              void* d_out, int out_size, void* d_ws, size_t ws_size,
                              hipStream_t stream) {
    const float* x         = (const float*)d_in[0];
    const float* q         = (const float*)d_in[1];
    const float* gate_w    = (const float*)d_in[2];
    const float* gate_b    = (const float*)d_in[3];
    const float* wk_cmp    = (const float*)d_in[4];
    const float* wv_cmp    = (const float*)d_in[5];
    const float* wk_slc    = (const float*)d_in[6];
    const float* wv_slc    = (const float*)d_in[7];
    const float* wk_win    = (const float*)d_in[8];
    const float* wv_win    = (const float*)d_in[9];
    const float* block_pos = (const float*)d_in[10];
    const float* ck1_w     = (const float*)d_in[11];
    const float* ck1_b     = (const float*)d_in[12];
    const float* ck2_w     = (const float*)d_in[13];
    const float* ck2_b     = (const float*)d_in[14];
    const float* cv1_w     = (const float*)d_in[15];
    const float* cv1_b     = (const float*)d_in[16];
    const float* cv2_w     = (const float*)d_in[17];
    const float* cv2_b     = (const float*)d_in[18];
    float* out = (float*)d_out;

    float* ws = (float*)d_ws;
    float* gates_lin = ws;                         // 1024*48
    float* k_cmp = gates_lin + T_LEN * 48;         // 1024*256 each
    float* v_cmp = k_cmp + T_LEN * KVD;
    float* k_slc = v_cmp + T_LEN * KVD;
    float* v_slc = k_slc + T_LEN * KVD;
    float* k_win = v_slc + T_LEN * KVD;
    float* v_win = k_win + T_LEN * KVD;
    float* ksum  = v_win + T_LEN * KVD;            // 63*4*64 each
    float* vsum  = ksum + NB * KVD;
    unsigned int* selmask_ws = (unsigned int*)(vsum + NB * KVD); // 4*1024*2

    dim3 blk(256);
    hipMemsetAsync(out, 0, (size_t)out_size * sizeof(float), stream);
    size_t smem_proj = 2 * 32 * 68 * sizeof(float);
    proj_all<<<dim3(25, 16), blk, smem_proj, stream>>>(
        x, gate_w, gate_b, wk_cmp, wv_cmp, wk_slc, wv_slc, wk_win, wv_win,
        gates_lin, k_cmp, v_cmp, k_slc, v_slc, k_win, v_win);
    nsa_summarize<<<dim3(16, NKV, 2), blk, 0, stream>>>(
        k_cmp, v_cmp, block_pos,
        ck1_w, ck1_b, ck2_w, ck2_b, cv1_w, cv1_b, cv2_w, cv2_b,
        ksum, vsum);
    size_t smem_att = 40192;
    // cmp (1024 blocks) and win-flash (256 blocks) are independent: one dispatch
    nsa_cmp_win<<<dim3(320, NKV), blk, smem_att, stream>>>(
        q, gates_lin, ksum, vsum, k_win, v_win, out, selmask_ws);
    // sel-flash needs selmask -> separate dispatch
    nsa_sel<<<dim3(T_LEN / TQ, NKV), blk, smem_att, stream>>>(
        q, gates_lin, k_slc, v_slc, selmask_ws, out);
}